// Round 1
// baseline (430.071 us; speedup 1.0000x reference)
//
#include <hip/hip_runtime.h>
#include <cstdint>

#define NN    50000
#define NE    1600000
#define DIN   256
#define DOUT  64
#define CAP   96      // max out-degree bucket capacity (Poisson(32): P(deg>=96) ~ 1e-18)
#define NPB   32      // nodes per block in gemm
#define KT    32      // k-tile staged in LDS for W

__device__ __forceinline__ float leaky01(float x) { return x >= 0.f ? x : 0.01f * x; }

__device__ __forceinline__ int   bcast_i(int v, int lane) {
  return __builtin_amdgcn_readlane(v, lane);
}
__device__ __forceinline__ float bcast_f(float v, int lane) {
  return __int_as_float(__builtin_amdgcn_readlane(__float_as_int(v), lane));
}

// -------------------------------------------------------------------------
// Kernel 1: H = leaky01(inp @ Wh), L = leaky01(inp @ Wl),
//           sh = H @ ah, sl = L @ al
// block = 256 threads (4 waves), 32 nodes/block.
// thread t: c = t&63 (output col), g = t>>6 (node-group of 8 nodes).
// Within a wave all 64 lanes share g and cover c=0..63 -> shfl reduce for s.
// -------------------------------------------------------------------------
__global__ __launch_bounds__(256) void gemm_kernel(
    const float* __restrict__ inp, const float* __restrict__ Wh,
    const float* __restrict__ Wl, const float* __restrict__ ah,
    const float* __restrict__ al, float* __restrict__ H,
    float* __restrict__ L, float* __restrict__ sh, float* __restrict__ sl)
{
  __shared__ float inT[NPB][DIN + 4];      // +4 pad, rows stay 16B-aligned (1040 B)
  __shared__ float wT[2][KT][DOUT];        // [which][kk][c] -> conflict-free reads

  const int t  = threadIdx.x;
  const int n0 = blockIdx.x * NPB;
  const int c  = t & 63;
  const int g  = t >> 6;                   // 0..3

  // Stage input tile as float4 (NPB*64 float4 = 2048; 8 per thread)
  for (int i = t; i < NPB * (DIN / 4); i += 256) {
    int r = i >> 6, c4 = i & 63;
    int n = n0 + r;
    float4 v = make_float4(0.f, 0.f, 0.f, 0.f);
    if (n < NN) v = ((const float4*)inp)[(size_t)n * (DIN / 4) + c4];
    *(float4*)&inT[r][c4 * 4] = v;
  }

  float accH[8], accL[8];
#pragma unroll
  for (int i = 0; i < 8; i++) { accH[i] = 0.f; accL[i] = 0.f; }

  for (int k0 = 0; k0 < DIN; k0 += KT) {
    __syncthreads();  // protects inT (first iter) and wT (prev iter reads)
    // stage W chunk: 2 * KT * 64 = 4096 floats, 16 per thread, coalesced
    for (int i = t; i < 2 * KT * DOUT; i += 256) {
      int which = i >> 11;            // KT*DOUT = 2048 per matrix
      int rem   = i & 2047;
      int kk = rem >> 6, cc = rem & 63;
      const float* W = which ? Wl : Wh;
      wT[which][kk][cc] = W[(size_t)(k0 + kk) * DOUT + cc];
    }
    __syncthreads();

#pragma unroll
    for (int kk = 0; kk < KT; kk += 4) {
      float wh0 = wT[0][kk + 0][c], wh1 = wT[0][kk + 1][c];
      float wh2 = wT[0][kk + 2][c], wh3 = wT[0][kk + 3][c];
      float wl0 = wT[1][kk + 0][c], wl1 = wT[1][kk + 1][c];
      float wl2 = wT[1][kk + 2][c], wl3 = wT[1][kk + 3][c];
#pragma unroll
      for (int i = 0; i < 8; i++) {
        float4 a = *(const float4*)&inT[g * 8 + i][k0 + kk];
        accH[i] += a.x * wh0 + a.y * wh1 + a.z * wh2 + a.w * wh3;
        accL[i] += a.x * wl0 + a.y * wl1 + a.z * wl2 + a.w * wl3;
      }
    }
  }

  const float a_h = ah[c];
  const float a_l = al[c];
#pragma unroll
  for (int i = 0; i < 8; i++) {
    int n = n0 + g * 8 + i;
    float hH = leaky01(accH[i]);
    float hL = leaky01(accL[i]);
    float ph = hH * a_h, pl = hL * a_l;
#pragma unroll
    for (int off = 32; off > 0; off >>= 1) {
      ph += __shfl_xor(ph, off);
      pl += __shfl_xor(pl, off);
    }
    if (n < NN) {
      H[(size_t)n * DOUT + c] = hH;
      L[(size_t)n * DOUT + c] = hL;
      if (c == 0) { sh[n] = ph; sl[n] = pl; }
    }
  }
}

// -------------------------------------------------------------------------
// Kernel 2: bucket-CSR build. deg[] must be pre-zeroed.
// -------------------------------------------------------------------------
__global__ __launch_bounds__(256) void scatter_kernel(
    const int* __restrict__ edge, int* __restrict__ deg, int* __restrict__ col)
{
  int e = blockIdx.x * blockDim.x + threadIdx.x;
  if (e >= NE) return;
  int src = edge[e];
  int dst = edge[NE + e];
  if ((unsigned)src >= NN || (unsigned)dst >= NN) return;  // defensive
  int pos = atomicAdd(&deg[src], 1);
  if (pos < CAP) col[(size_t)src * CAP + pos] = dst;
}

// -------------------------------------------------------------------------
// Kernel 3: one wave per node; lane d owns feature dim d. No float atomics.
// -------------------------------------------------------------------------
__global__ __launch_bounds__(256) void agg_kernel(
    const float* __restrict__ H, const float* __restrict__ L,
    const float* __restrict__ sh, const float* __restrict__ sl,
    const int* __restrict__ deg, const int* __restrict__ col,
    float* __restrict__ out)
{
  int wave = (blockIdx.x * blockDim.x + threadIdx.x) >> 6;
  int lane = threadIdx.x & 63;
  if (wave >= NN) return;
  const int n = wave;
  int d = deg[n]; if (d > CAP) d = CAP;

  const float shn = sh[n];
  const float sln = sl[n];
  const int* cl = col + (size_t)n * CAP;

  float accH = 0.f, accL = 0.f, rsH = 0.f, rsL = 0.f;

  for (int base = 0; base < d; base += 64) {
    int m = d - base; if (m > 64) m = 64;
    // cooperative, coalesced load of up to 64 edge targets + their scalars
    int   dst_l = 0;
    float eh_l = 0.f, el_l = 0.f;
    if (lane < m) {
      dst_l = cl[base + lane];
      float xh = shn - sh[dst_l];
      xh = (xh >= 0.f) ? xh : 0.2f * xh;
      eh_l = __expf(-xh);
      float xl = sln + sl[dst_l];
      xl = (xl >= 0.f) ? xl : 0.2f * xl;
      el_l = __expf(-xl);
    }
    for (int j = 0; j < m; j++) {
      int   dst = bcast_i(dst_l, j);
      float eh  = bcast_f(eh_l, j);
      float el  = bcast_f(el_l, j);
      accH += eh * H[(size_t)dst * DOUT + lane];
      accL += el * L[(size_t)dst * DOUT + lane];
      rsH += eh;
      rsL += el;
    }
  }

  float oh = accH / (rsH + 1e-16f);
  float ol = accL / (rsL + 1e-16f);
  out[(size_t)n * 128 + lane]      = leaky01(oh);
  out[(size_t)n * 128 + 64 + lane] = leaky01(ol);
}

// -------------------------------------------------------------------------
extern "C" void kernel_launch(void* const* d_in, const int* in_sizes, int n_in,
                              void* d_out, int out_size, void* d_ws, size_t ws_size,
                              hipStream_t stream) {
  const float* inp = (const float*)d_in[0];
  const int*   edge = (const int*)d_in[1];
  const float* Wh  = (const float*)d_in[2];
  const float* Wl  = (const float*)d_in[3];
  const float* ah  = (const float*)d_in[4];
  const float* al  = (const float*)d_in[5];
  float* out = (float*)d_out;

  char* ws = (char*)d_ws;
  float* H   = (float*)(ws + 0);           // 12,800,000 B
  float* L   = (float*)(ws + 12800000);    // 12,800,000 B
  float* sh  = (float*)(ws + 25600000);    //    200,192 B
  float* sl  = (float*)(ws + 25800192);    //    200,192 B
  int*   deg = (int*)  (ws + 26000384);    //    200,192 B
  int*   col = (int*)  (ws + 26200576);    // 19,200,000 B -> total 45,400,576 B

  hipMemsetAsync(deg, 0, NN * sizeof(int), stream);
  gemm_kernel<<<(NN + NPB - 1) / NPB, 256, 0, stream>>>(inp, Wh, Wl, ah, al, H, L, sh, sl);
  scatter_kernel<<<(NE + 255) / 256, 256, 0, stream>>>(edge, deg, col);
  agg_kernel<<<NN / 4, 256, 0, stream>>>(H, L, sh, sl, deg, col, out);
}

// Round 2
// 378.821 us; speedup vs baseline: 1.1353x; 1.1353x over previous
//
#include <hip/hip_runtime.h>
#include <hip/hip_bf16.h>
#include <cstdint>

#define NN    50000
#define NE    1600000
#define DIN   256
#define DOUT  64
#define CAP   96      // max out-degree bucket capacity (Poisson(32): P(deg>=96) ~ 1e-18)
#define NPB   32      // nodes per block in gemm
#define DEGS  16      // deg stride: one counter per 64B line (atomic contention fix)

__device__ __forceinline__ float leaky01(float x) { return x >= 0.f ? x : 0.01f * x; }

__device__ __forceinline__ int   bcast_i(int v, int lane) {
  return __builtin_amdgcn_readlane(v, lane);
}
__device__ __forceinline__ float bcast_f(float v, int lane) {
  return __int_as_float(__builtin_amdgcn_readlane(__float_as_int(v), lane));
}

// bf16 pair unpack: u = (Lbits<<16) | Hbits
__device__ __forceinline__ float bfH(uint32_t u) { return __uint_as_float(u << 16); }
__device__ __forceinline__ float bfL(uint32_t u) { return __uint_as_float(u & 0xffff0000u); }

// -------------------------------------------------------------------------
// Kernel 1: H = leaky01(inp @ Wh), L = leaky01(inp @ Wl)  -> packed bf16 HL
//           sh = H @ ah, sl = L @ al                      -> packed f32  ss
// block = 256 threads (4 waves), 32 nodes/block.
// thread t: c = t&63 (output col), g = t>>6 (node-group of 8 nodes).
// All lanes of a wave share g -> inT reads are same-address broadcasts
// (conflict-free, no padding needed). W read from global (L2-resident,
// 256B coalesced per wave-load). One __syncthreads total.
// -------------------------------------------------------------------------
__global__ __launch_bounds__(256) void gemm_kernel(
    const float* __restrict__ inp, const float* __restrict__ Wh,
    const float* __restrict__ Wl, const float* __restrict__ ah,
    const float* __restrict__ al, uint32_t* __restrict__ HL,
    float2* __restrict__ ss)
{
  __shared__ float inT[NPB][DIN];          // 32 KB -> 5 blocks/CU

  const int t  = threadIdx.x;
  const int n0 = blockIdx.x * NPB;
  const int c  = t & 63;
  const int g  = t >> 6;                   // 0..3

  // Stage input tile as float4 (2048 float4; 8 per thread, coalesced)
  for (int i = t; i < NPB * (DIN / 4); i += 256) {
    int r = i >> 6, c4 = i & 63;
    int n = n0 + r;
    float4 v = make_float4(0.f, 0.f, 0.f, 0.f);
    if (n < NN) v = ((const float4*)inp)[(size_t)n * (DIN / 4) + c4];
    *(float4*)&inT[r][c4 * 4] = v;
  }
  __syncthreads();

  float accH[8], accL[8];
#pragma unroll
  for (int i = 0; i < 8; i++) { accH[i] = 0.f; accL[i] = 0.f; }

  const float* WhC = Wh + c;               // column c, row-stride DOUT
  const float* WlC = Wl + c;

#pragma unroll 2
  for (int k = 0; k < DIN; k += 4) {
    float wh0 = WhC[(k + 0) * DOUT], wh1 = WhC[(k + 1) * DOUT];
    float wh2 = WhC[(k + 2) * DOUT], wh3 = WhC[(k + 3) * DOUT];
    float wl0 = WlC[(k + 0) * DOUT], wl1 = WlC[(k + 1) * DOUT];
    float wl2 = WlC[(k + 2) * DOUT], wl3 = WlC[(k + 3) * DOUT];
#pragma unroll
    for (int i = 0; i < 8; i++) {
      float4 a = *(const float4*)&inT[g * 8 + i][k];
      accH[i] += a.x * wh0 + a.y * wh1 + a.z * wh2 + a.w * wh3;
      accL[i] += a.x * wl0 + a.y * wl1 + a.z * wl2 + a.w * wl3;
    }
  }

  const float a_h = ah[c];
  const float a_l = al[c];
#pragma unroll
  for (int i = 0; i < 8; i++) {
    int n = n0 + g * 8 + i;
    float hH = leaky01(accH[i]);
    float hL = leaky01(accL[i]);
    float ph = hH * a_h, pl = hL * a_l;
#pragma unroll
    for (int off = 32; off > 0; off >>= 1) {
      ph += __shfl_xor(ph, off);
      pl += __shfl_xor(pl, off);
    }
    if (n < NN) {
      __hip_bfloat162 p;
      p.x = __float2bfloat16(hH);          // low 16 bits
      p.y = __float2bfloat16(hL);          // high 16 bits
      ((__hip_bfloat162*)HL)[(size_t)n * DOUT + c] = p;
      if (c == 0) ss[n] = make_float2(ph, pl);
    }
  }
}

// -------------------------------------------------------------------------
// Kernel 2: bucket-CSR build. deg[] (stride DEGS) must be pre-zeroed.
// -------------------------------------------------------------------------
__global__ __launch_bounds__(256) void scatter_kernel(
    const int* __restrict__ edge, int* __restrict__ deg, int* __restrict__ col)
{
  int e = blockIdx.x * blockDim.x + threadIdx.x;
  if (e >= NE) return;
  int src = edge[e];
  int dst = edge[NE + e];
  if ((unsigned)src >= NN || (unsigned)dst >= NN) return;  // defensive
  int pos = atomicAdd(&deg[src * DEGS], 1);
  if (pos < CAP) col[(size_t)src * CAP + pos] = dst;
}

// -------------------------------------------------------------------------
// Kernel 3: one wave per node; lane d owns feature dim d. No float atomics.
// Per edge: one 4B/lane gather of the packed bf16 (H,L) pair.
// -------------------------------------------------------------------------
__global__ __launch_bounds__(256) void agg_kernel(
    const uint32_t* __restrict__ HL, const float2* __restrict__ ss,
    const int* __restrict__ deg, const int* __restrict__ col,
    float* __restrict__ out)
{
  int wave = (blockIdx.x * blockDim.x + threadIdx.x) >> 6;
  int lane = threadIdx.x & 63;
  if (wave >= NN) return;
  const int n = wave;
  int d = deg[n * DEGS]; if (d > CAP) d = CAP;

  const float2 sn = ss[n];
  const int* cl = col + (size_t)n * CAP;

  float accH = 0.f, accL = 0.f, rsH = 0.f, rsL = 0.f;

  for (int base = 0; base < d; base += 64) {
    int m = d - base; if (m > 64) m = 64;
    int   dst_l = 0;
    float eh_l = 0.f, el_l = 0.f;
    if (lane < m) {
      dst_l = cl[base + lane];
      float2 sd = ss[dst_l];
      float xh = sn.x - sd.x;
      xh = (xh >= 0.f) ? xh : 0.2f * xh;
      eh_l = __expf(-xh);
      float xl = sn.y + sd.y;
      xl = (xl >= 0.f) ? xl : 0.2f * xl;
      el_l = __expf(-xl);
    }
    for (int j = 0; j < m; j++) {
      int      dst = bcast_i(dst_l, j);
      float    eh  = bcast_f(eh_l, j);
      float    el  = bcast_f(el_l, j);
      uint32_t u   = HL[(size_t)dst * DOUT + lane];
      accH += eh * bfH(u);
      accL += el * bfL(u);
      rsH += eh;
      rsL += el;
    }
  }

  float oh = accH / (rsH + 1e-16f);
  float ol = accL / (rsL + 1e-16f);
  out[(size_t)n * 128 + lane]      = leaky01(oh);
  out[(size_t)n * 128 + 64 + lane] = leaky01(ol);
}

// -------------------------------------------------------------------------
extern "C" void kernel_launch(void* const* d_in, const int* in_sizes, int n_in,
                              void* d_out, int out_size, void* d_ws, size_t ws_size,
                              hipStream_t stream) {
  const float* inp  = (const float*)d_in[0];
  const int*   edge = (const int*)d_in[1];
  const float* Wh   = (const float*)d_in[2];
  const float* Wl   = (const float*)d_in[3];
  const float* ah   = (const float*)d_in[4];
  const float* al   = (const float*)d_in[5];
  float* out = (float*)d_out;

  char* ws = (char*)d_ws;
  uint32_t* HL  = (uint32_t*)(ws + 0);          // 50000*64*4  = 12,800,000 B
  float2*   ss  = (float2*)  (ws + 12800000);   // 50000*8     =    400,000 B
  int*      deg = (int*)     (ws + 13200000);   // 50000*16*4  =  3,200,000 B
  int*      col = (int*)     (ws + 16400000);   // 50000*96*4  = 19,200,000 B

  hipMemsetAsync(deg, 0, (size_t)NN * DEGS * sizeof(int), stream);
  scatter_kernel<<<(NE + 255) / 256, 256, 0, stream>>>(edge, deg, col);
  gemm_kernel<<<(NN + NPB - 1) / NPB, 256, 0, stream>>>(inp, Wh, Wl, ah, al, HL, ss);
  agg_kernel<<<NN / 4, 256, 0, stream>>>(HL, ss, deg, col, out);
}

// Round 3
// 330.145 us; speedup vs baseline: 1.3027x; 1.1474x over previous
//
#include <hip/hip_runtime.h>
#include <hip/hip_bf16.h>
#include <cstdint>

#define NN    50000
#define NE    1600000
#define DIN   256
#define DOUT  64
#define NPB   32      // nodes per block in gemm role
#define CAPS  96      // bucket stride (ints): slot 0 = count, slots 1..95 = dsts
#define CAPD  95      // max stored out-degree (Poisson(32): P(>=95) ~ 1e-18)

// grid layout for fused kernel: idx%5 in {0,1} -> scatter, {2,3,4} -> gemm
#define GROUPS 521                    // 521*3 = 1563 gemm tiles = ceil(NN/NPB)
#define GFUSED (GROUPS * 5)           // 2605 blocks
#define NSCT   (GROUPS * 2 * 256)     // 266752 scatter threads
#define EPT    6                      // 6*266752 >= NE

__device__ __forceinline__ float leaky01(float x) { return x >= 0.f ? x : 0.01f * x; }

__device__ __forceinline__ int   bcast_i(int v, int lane) {
  return __builtin_amdgcn_readlane(v, lane);
}
__device__ __forceinline__ float bcast_f(float v, int lane) {
  return __int_as_float(__builtin_amdgcn_readlane(__float_as_int(v), lane));
}

// bf16 pair unpack: u = (Lbits<<16) | Hbits
__device__ __forceinline__ float bfH(uint32_t u) { return __uint_as_float(u << 16); }
__device__ __forceinline__ float bfL(uint32_t u) { return __uint_as_float(u & 0xffff0000u); }

// -------------------------------------------------------------------------
// zero bucket counters (col[n*CAPS])
// -------------------------------------------------------------------------
__global__ __launch_bounds__(256) void zero_kernel(int* __restrict__ col)
{
  int n = blockIdx.x * 256 + threadIdx.x;
  if (n < NN) col[(size_t)n * CAPS] = 0;
}

// -------------------------------------------------------------------------
// Fused kernel, block-role specialization:
//  role scatter (fabric-bound, VALU idle): bucket-CSR build via returning
//    atomics + scattered stores. Runs in the shadow of the gemm blocks.
//  role gemm (VALU-bound, low fabric traffic):
//    H = leaky01(inp@Wh), L = leaky01(inp@Wl) -> packed bf16 HL
//    sh = H@ah, sl = L@al                     -> packed f32 ss
// -------------------------------------------------------------------------
__global__ __launch_bounds__(256) void fused_kernel(
    const float* __restrict__ inp, const float* __restrict__ Wh,
    const float* __restrict__ Wl, const float* __restrict__ ah,
    const float* __restrict__ al, const int* __restrict__ edge,
    int* __restrict__ col, uint32_t* __restrict__ HL,
    float2* __restrict__ ss)
{
  __shared__ float inT[NPB][DIN];          // 32 KB

  const int idx = blockIdx.x;
  const int q = idx / 5, r = idx % 5;
  const int t = threadIdx.x;

  if (r < 2) {
    // ---------------- scatter role ----------------
    const int st = (q * 2 + r) * 256 + t;  // 0 .. NSCT-1
#pragma unroll
    for (int i = 0; i < EPT; i++) {
      int e = i * NSCT + st;               // coalesced within each wave
      if (e < NE) {
        int src = edge[e];
        int dst = edge[NE + e];
        int pos = atomicAdd(&col[(size_t)src * CAPS], 1);
        if (pos < CAPD) col[(size_t)src * CAPS + 1 + pos] = dst;
      }
    }
    return;
  }

  // ---------------- gemm role ----------------
  const int gid = q * 3 + (r - 2);         // 0 .. 1562
  const int n0 = gid * NPB;
  const int c  = t & 63;
  const int g  = t >> 6;                   // 0..3

  for (int i = t; i < NPB * (DIN / 4); i += 256) {
    int rr = i >> 6, c4 = i & 63;
    int n = n0 + rr;
    float4 v = make_float4(0.f, 0.f, 0.f, 0.f);
    if (n < NN) v = ((const float4*)inp)[(size_t)n * (DIN / 4) + c4];
    *(float4*)&inT[rr][c4 * 4] = v;
  }
  __syncthreads();

  float accH[8], accL[8];
#pragma unroll
  for (int i = 0; i < 8; i++) { accH[i] = 0.f; accL[i] = 0.f; }

  const float* WhC = Wh + c;               // column c, row-stride DOUT
  const float* WlC = Wl + c;

#pragma unroll 2
  for (int k = 0; k < DIN; k += 4) {
    float wh0 = WhC[(k + 0) * DOUT], wh1 = WhC[(k + 1) * DOUT];
    float wh2 = WhC[(k + 2) * DOUT], wh3 = WhC[(k + 3) * DOUT];
    float wl0 = WlC[(k + 0) * DOUT], wl1 = WlC[(k + 1) * DOUT];
    float wl2 = WlC[(k + 2) * DOUT], wl3 = WlC[(k + 3) * DOUT];
#pragma unroll
    for (int i = 0; i < 8; i++) {
      float4 a = *(const float4*)&inT[g * 8 + i][k];
      accH[i] += a.x * wh0 + a.y * wh1 + a.z * wh2 + a.w * wh3;
      accL[i] += a.x * wl0 + a.y * wl1 + a.z * wl2 + a.w * wl3;
    }
  }

  const float a_h = ah[c];
  const float a_l = al[c];
#pragma unroll
  for (int i = 0; i < 8; i++) {
    int n = n0 + g * 8 + i;
    float hH = leaky01(accH[i]);
    float hL = leaky01(accL[i]);
    float ph = hH * a_h, pl = hL * a_l;
#pragma unroll
    for (int off = 32; off > 0; off >>= 1) {
      ph += __shfl_xor(ph, off);
      pl += __shfl_xor(pl, off);
    }
    if (n < NN) {
      __hip_bfloat162 p;
      p.x = __float2bfloat16(hH);          // low 16 bits
      p.y = __float2bfloat16(hL);          // high 16 bits
      ((__hip_bfloat162*)HL)[(size_t)n * DOUT + c] = p;
      if (c == 0) ss[n] = make_float2(ph, pl);
    }
  }
}

// -------------------------------------------------------------------------
// agg: one wave per node; lane d owns feature dim d. No float atomics.
// Bucket: count at col[n*CAPS], dsts at col[n*CAPS+1 ...].
// -------------------------------------------------------------------------
__global__ __launch_bounds__(256) void agg_kernel(
    const uint32_t* __restrict__ HL, const float2* __restrict__ ss,
    const int* __restrict__ col, float* __restrict__ out)
{
  int wave = (blockIdx.x * blockDim.x + threadIdx.x) >> 6;
  int lane = threadIdx.x & 63;
  if (wave >= NN) return;
  const int n = wave;
  const int* cl = col + (size_t)n * CAPS;
  int d = cl[0]; if (d > CAPD) d = CAPD;

  const float2 sn = ss[n];

  float accH = 0.f, accL = 0.f, rsH = 0.f, rsL = 0.f;

  for (int base = 0; base < d; base += 64) {
    int m = d - base; if (m > 64) m = 64;
    int   dst_l = 0;
    float eh_l = 0.f, el_l = 0.f;
    if (lane < m) {
      dst_l = cl[1 + base + lane];
      float2 sd = ss[dst_l];
      float xh = sn.x - sd.x;
      xh = (xh >= 0.f) ? xh : 0.2f * xh;
      eh_l = __expf(-xh);
      float xl = sn.y + sd.y;
      xl = (xl >= 0.f) ? xl : 0.2f * xl;
      el_l = __expf(-xl);
    }
    for (int j = 0; j < m; j++) {
      int      dst = bcast_i(dst_l, j);
      float    eh  = bcast_f(eh_l, j);
      float    el  = bcast_f(el_l, j);
      uint32_t u   = HL[(size_t)dst * DOUT + lane];
      accH += eh * bfH(u);
      accL += el * bfL(u);
      rsH += eh;
      rsL += el;
    }
  }

  float oh = accH / (rsH + 1e-16f);
  float ol = accL / (rsL + 1e-16f);
  out[(size_t)n * 128 + lane]      = leaky01(oh);
  out[(size_t)n * 128 + 64 + lane] = leaky01(ol);
}

// -------------------------------------------------------------------------
extern "C" void kernel_launch(void* const* d_in, const int* in_sizes, int n_in,
                              void* d_out, int out_size, void* d_ws, size_t ws_size,
                              hipStream_t stream) {
  const float* inp  = (const float*)d_in[0];
  const int*   edge = (const int*)d_in[1];
  const float* Wh   = (const float*)d_in[2];
  const float* Wl   = (const float*)d_in[3];
  const float* ah   = (const float*)d_in[4];
  const float* al   = (const float*)d_in[5];
  float* out = (float*)d_out;

  char* ws = (char*)d_ws;
  uint32_t* HL  = (uint32_t*)(ws + 0);          // 50000*64*4  = 12,800,000 B
  float2*   ss  = (float2*)  (ws + 12800000);   // 50000*8     =    400,000 B
  int*      col = (int*)     (ws + 13200000);   // 50000*96*4  = 19,200,000 B

  zero_kernel<<<(NN + 255) / 256, 256, 0, stream>>>(col);
  fused_kernel<<<GFUSED, 256, 0, stream>>>(inp, Wh, Wl, ah, al, edge, col, HL, ss);
  agg_kernel<<<NN / 4, 256, 0, stream>>>(HL, ss, col, out);
}

// Round 4
// 239.700 us; speedup vs baseline: 1.7942x; 1.3773x over previous
//
#include <hip/hip_runtime.h>
#include <hip/hip_bf16.h>
#include <cstdint>

#define NN    50000
#define NE    1600000
#define DIN   256
#define DOUT  64
#define NPB   32      // nodes per block in gemm role
#define CAPS  96      // bucket stride (ints): slot 0 = count, slots 1..95 = dsts
#define CAPD  95      // max stored out-degree (Poisson(32): P(>=95) ~ 1e-18)

#define BKT   196     // coarse buckets: src>>8 (256 nodes each), 49999>>8 = 195
#define BCAP  10240   // edges per coarse bucket capacity (mean 8163, sigma 90)
#define EPB   4096    // edges per binning block
#define EPT   16      // EPB / 256
#define NBIN  391     // ceil(NE / EPB)
#define NGEMM 1563    // ceil(NN / NPB)

__device__ __forceinline__ float leaky01(float x) { return x >= 0.f ? x : 0.01f * x; }

__device__ __forceinline__ int   bcast_i(int v, int lane) {
  return __builtin_amdgcn_readlane(v, lane);
}
__device__ __forceinline__ float bcast_f(float v, int lane) {
  return __int_as_float(__builtin_amdgcn_readlane(__float_as_int(v), lane));
}

// bf16 pair unpack: u = (Lbits<<16) | Hbits
__device__ __forceinline__ float bfH(uint32_t u) { return __uint_as_float(u << 16); }
__device__ __forceinline__ float bfL(uint32_t u) { return __uint_as_float(u & 0xffff0000u); }

// -------------------------------------------------------------------------
// zero the 196 coarse-bucket cursors
// -------------------------------------------------------------------------
__global__ __launch_bounds__(256) void zero_kernel(int* __restrict__ cursor)
{
  int t = threadIdx.x;
  if (t < BKT) cursor[t] = 0;
}

// -------------------------------------------------------------------------
// Fused kernel:
//  blocks [0, NBIN): binning role — LDS counting-sort of 4096 edges into 196
//    coarse buckets (src>>8); one global atomic per (block,bucket); coalesced
//    run writes of packed (src<<16)|dst. Replaces the fabric-bound scatter.
//  blocks [NBIN, NBIN+NGEMM): gemm role —
//    H = leaky01(inp@Wh), L = leaky01(inp@Wl) -> packed bf16 HL
//    sh = H@ah, sl = L@al                     -> packed f32 ss
// Shared memory is a 32 KB overlay (gemm tile / binning stage+hists).
// -------------------------------------------------------------------------
__global__ __launch_bounds__(256) void fused_kernel(
    const float* __restrict__ inp, const float* __restrict__ Wh,
    const float* __restrict__ Wl, const float* __restrict__ ah,
    const float* __restrict__ al, const int* __restrict__ edge,
    int* __restrict__ cursor, uint32_t* __restrict__ binned,
    uint32_t* __restrict__ HL, float2* __restrict__ ss)
{
  __shared__ __align__(16) char smem[NPB * DIN * 4];   // 32 KB overlay

  const int idx = blockIdx.x;
  const int t = threadIdx.x;

  if (idx < NBIN) {
    // ---------------- binning role ----------------
    uint32_t* stage  = (uint32_t*)smem;                 // 16384 B
    int*      hist   = (int*)(smem + 16384);            // 784 B
    int*      cur    = (int*)(smem + 17168);            // 784 B
    int*      base_g = (int*)(smem + 17952);            // 784 B
    int*      scan_s = (int*)(smem + 18736);            // 788 B

    const int e0 = idx * EPB;
    uint32_t v[EPT];
#pragma unroll
    for (int i = 0; i < EPT; i++) {
      int e = e0 + i * 256 + t;
      if (e < NE) {
        uint32_t s = (uint32_t)edge[e];
        uint32_t d = (uint32_t)edge[NE + e];
        v[i] = (s << 16) | d;            // bin = v >> 24 = src >> 8
      } else {
        v[i] = 0xFFFFFFFFu;              // bin 255 -> skipped
      }
    }
    for (int b = t; b < BKT; b += 256) { hist[b] = 0; cur[b] = 0; }
    __syncthreads();
#pragma unroll
    for (int i = 0; i < EPT; i++) {
      int b = v[i] >> 24;
      if (b < BKT) atomicAdd(&hist[b], 1);
    }
    __syncthreads();
    if (t == 0) {
      int acc = 0;
      for (int b = 0; b < BKT; b++) { scan_s[b] = acc; acc += hist[b]; }
      scan_s[BKT] = acc;
    }
    __syncthreads();
    for (int b = t; b < BKT; b += 256) {
      int h = hist[b];
      base_g[b] = h ? atomicAdd(&cursor[b], h) : 0;
    }
    __syncthreads();
#pragma unroll
    for (int i = 0; i < EPT; i++) {
      int b = v[i] >> 24;
      if (b < BKT) {
        int pos = atomicAdd(&cur[b], 1);
        stage[scan_s[b] + pos] = v[i];
      }
    }
    __syncthreads();
    const int total = scan_s[BKT];
    for (int i = t; i < total; i += 256) {
      // largest b with scan_s[b] <= i
      int lo = 0, hi = BKT - 1;
      while (lo < hi) { int mid = (lo + hi + 1) >> 1; if (scan_s[mid] <= i) lo = mid; else hi = mid - 1; }
      int ofs = base_g[lo] + (i - scan_s[lo]);
      if (ofs < BCAP) binned[(size_t)lo * BCAP + ofs] = stage[i];
    }
    return;
  }

  // ---------------- gemm role ----------------
  float (*inT)[DIN] = (float(*)[DIN])smem;

  const int gid = idx - NBIN;              // 0 .. NGEMM-1
  const int n0 = gid * NPB;
  const int c  = t & 63;
  const int g  = t >> 6;                   // 0..3

  for (int i = t; i < NPB * (DIN / 4); i += 256) {
    int rr = i >> 6, c4 = i & 63;
    int n = n0 + rr;
    float4 vv = make_float4(0.f, 0.f, 0.f, 0.f);
    if (n < NN) vv = ((const float4*)inp)[(size_t)n * (DIN / 4) + c4];
    *(float4*)&inT[rr][c4 * 4] = vv;
  }
  __syncthreads();

  float accH[8], accL[8];
#pragma unroll
  for (int i = 0; i < 8; i++) { accH[i] = 0.f; accL[i] = 0.f; }

  const float* WhC = Wh + c;               // column c, row-stride DOUT
  const float* WlC = Wl + c;

#pragma unroll 2
  for (int k = 0; k < DIN; k += 4) {
    float wh0 = WhC[(k + 0) * DOUT], wh1 = WhC[(k + 1) * DOUT];
    float wh2 = WhC[(k + 2) * DOUT], wh3 = WhC[(k + 3) * DOUT];
    float wl0 = WlC[(k + 0) * DOUT], wl1 = WlC[(k + 1) * DOUT];
    float wl2 = WlC[(k + 2) * DOUT], wl3 = WlC[(k + 3) * DOUT];
#pragma unroll
    for (int i = 0; i < 8; i++) {
      float4 a = *(const float4*)&inT[g * 8 + i][k];
      accH[i] += a.x * wh0 + a.y * wh1 + a.z * wh2 + a.w * wh3;
      accL[i] += a.x * wl0 + a.y * wl1 + a.z * wl2 + a.w * wl3;
    }
  }

  const float a_h = ah[c];
  const float a_l = al[c];
#pragma unroll
  for (int i = 0; i < 8; i++) {
    int n = n0 + g * 8 + i;
    float hH = leaky01(accH[i]);
    float hL = leaky01(accL[i]);
    float ph = hH * a_h, pl = hL * a_l;
#pragma unroll
    for (int off = 32; off > 0; off >>= 1) {
      ph += __shfl_xor(ph, off);
      pl += __shfl_xor(pl, off);
    }
    if (n < NN) {
      __hip_bfloat162 p;
      p.x = __float2bfloat16(hH);          // low 16 bits
      p.y = __float2bfloat16(hL);          // high 16 bits
      ((__hip_bfloat162*)HL)[(size_t)n * DOUT + c] = p;
      if (c == 0) ss[n] = make_float2(ph, pl);
    }
  }
}

// -------------------------------------------------------------------------
// CSR build: one block per coarse bucket. LDS per-node counters; scattered
// writes confined to this bucket's 98 KB col window (L2-local, one XCD).
// -------------------------------------------------------------------------
__global__ __launch_bounds__(256) void csr_kernel(
    const uint32_t* __restrict__ binned, const int* __restrict__ cursor,
    int* __restrict__ col)
{
  __shared__ int cnt[256];
  const int b = blockIdx.x;                // 0..BKT-1
  const int t = threadIdx.x;
  cnt[t] = 0;
  __syncthreads();
  int n = cursor[b]; if (n > BCAP) n = BCAP;
  const uint32_t* eb = binned + (size_t)b * BCAP;
  for (int i = t; i < n; i += 256) {
    uint32_t v = eb[i];
    int src = v >> 16, dst = v & 0xffff;
    int pos = atomicAdd(&cnt[src & 255], 1);
    if (pos < CAPD) col[(size_t)src * CAPS + 1 + pos] = dst;
  }
  __syncthreads();
  int node = (b << 8) + t;
  if (node < NN) {
    int c = cnt[t]; if (c > CAPD) c = CAPD;
    col[(size_t)node * CAPS] = c;
  }
}

// -------------------------------------------------------------------------
// agg: one wave per node; lane d owns feature dim d. No float atomics.
// j-loop unrolled x4 -> 4 outstanding gathers per wave (latency fix).
// -------------------------------------------------------------------------
__global__ __launch_bounds__(256) void agg_kernel(
    const uint32_t* __restrict__ HL, const float2* __restrict__ ss,
    const int* __restrict__ col, float* __restrict__ out)
{
  int wave = (blockIdx.x * blockDim.x + threadIdx.x) >> 6;
  int lane = threadIdx.x & 63;
  if (wave >= NN) return;
  const int n = wave;
  const int* cl = col + (size_t)n * CAPS;
  int d = cl[0]; if (d > CAPD) d = CAPD;

  const float2 sn = ss[n];

  float accH = 0.f, accL = 0.f, rsH = 0.f, rsL = 0.f;

  for (int base = 0; base < d; base += 64) {
    int m = d - base; if (m > 64) m = 64;
    int   dst_l = 0;
    float eh_l = 0.f, el_l = 0.f;
    if (lane < m) {
      dst_l = cl[1 + base + lane];
      float2 sd = ss[dst_l];
      float xh = sn.x - sd.x;
      xh = (xh >= 0.f) ? xh : 0.2f * xh;
      eh_l = __expf(-xh);
      float xl = sn.y + sd.y;
      xl = (xl >= 0.f) ? xl : 0.2f * xl;
      el_l = __expf(-xl);
    }
    int j = 0;
    for (; j + 4 <= m; j += 4) {
      int d0 = bcast_i(dst_l, j + 0), d1 = bcast_i(dst_l, j + 1);
      int d2 = bcast_i(dst_l, j + 2), d3 = bcast_i(dst_l, j + 3);
      uint32_t u0 = HL[(size_t)d0 * DOUT + lane];
      uint32_t u1 = HL[(size_t)d1 * DOUT + lane];
      uint32_t u2 = HL[(size_t)d2 * DOUT + lane];
      uint32_t u3 = HL[(size_t)d3 * DOUT + lane];
      float e0 = bcast_f(eh_l, j + 0), f0 = bcast_f(el_l, j + 0);
      float e1 = bcast_f(eh_l, j + 1), f1 = bcast_f(el_l, j + 1);
      float e2 = bcast_f(eh_l, j + 2), f2 = bcast_f(el_l, j + 2);
      float e3 = bcast_f(eh_l, j + 3), f3 = bcast_f(el_l, j + 3);
      accH += e0 * bfH(u0); accL += f0 * bfL(u0);
      accH += e1 * bfH(u1); accL += f1 * bfL(u1);
      accH += e2 * bfH(u2); accL += f2 * bfL(u2);
      accH += e3 * bfH(u3); accL += f3 * bfL(u3);
      rsH += e0 + e1 + e2 + e3;
      rsL += f0 + f1 + f2 + f3;
    }
    for (; j < m; j++) {
      int      dst = bcast_i(dst_l, j);
      float    eh  = bcast_f(eh_l, j);
      float    el  = bcast_f(el_l, j);
      uint32_t u   = HL[(size_t)dst * DOUT + lane];
      accH += eh * bfH(u);
      accL += el * bfL(u);
      rsH += eh;
      rsL += el;
    }
  }

  float oh = accH / (rsH + 1e-16f);
  float ol = accL / (rsL + 1e-16f);
  out[(size_t)n * 128 + lane]      = leaky01(oh);
  out[(size_t)n * 128 + 64 + lane] = leaky01(ol);
}

// -------------------------------------------------------------------------
extern "C" void kernel_launch(void* const* d_in, const int* in_sizes, int n_in,
                              void* d_out, int out_size, void* d_ws, size_t ws_size,
                              hipStream_t stream) {
  const float* inp  = (const float*)d_in[0];
  const int*   edge = (const int*)d_in[1];
  const float* Wh   = (const float*)d_in[2];
  const float* Wl   = (const float*)d_in[3];
  const float* ah   = (const float*)d_in[4];
  const float* al   = (const float*)d_in[5];
  float* out = (float*)d_out;

  char* ws = (char*)d_ws;
  uint32_t* HL     = (uint32_t*)(ws + 0);          // 12,800,000 B
  float2*   ss     = (float2*)  (ws + 12800000);   //    400,000 B
  int*      col    = (int*)     (ws + 13200000);   // 19,200,000 B
  uint32_t* binned = (uint32_t*)(ws + 32400000);   //  8,028,160 B
  int*      cursor = (int*)     (ws + 40428160);   //        784 B

  zero_kernel<<<1, 256, 0, stream>>>(cursor);
  fused_kernel<<<NBIN + NGEMM, 256, 0, stream>>>(inp, Wh, Wl, ah, al, edge,
                                                 cursor, binned, HL, ss);
  csr_kernel<<<BKT, 256, 0, stream>>>(binned, cursor, col);
  agg_kernel<<<NN / 4, 256, 0, stream>>>(HL, ss, col, out);
}

// Round 5
// 218.658 us; speedup vs baseline: 1.9669x; 1.0962x over previous
//
#include <hip/hip_runtime.h>
#include <hip/hip_bf16.h>
#include <cstdint>

#define NN    50000
#define NE    1600000
#define DIN   256
#define DOUT  64
#define CAPS  96      // bucket stride (ints): slot 0 = count, slots 1..95 = dsts
#define CAPD  95      // max stored out-degree (Poisson(32): P(>=95) ~ 1e-18)

#define BKT   196     // coarse buckets: src>>8 (256 nodes each), 49999>>8 = 195
#define BCAP  10240   // edges per coarse bucket capacity (mean 8192, sigma 90)
#define EPB   4096    // edges per binning block
#define EPT   16      // EPB / 256
#define NBIN  391     // ceil(NE / EPB)
#define MTB   64      // rows per gemm block
#define NGEMM 782     // ceil(NN / MTB)

typedef __attribute__((ext_vector_type(8))) short frag8;   // 8 bf16 (4 VGPRs)
typedef __attribute__((ext_vector_type(4))) float fragc;   // 4 fp32 acc

union PK { __hip_bfloat162 b2; uint32_t u; };
union CH { frag8 v; uint32_t u[4]; };

__device__ __forceinline__ float leaky01(float x) { return x >= 0.f ? x : 0.01f * x; }

__device__ __forceinline__ uint32_t pk2(float lo, float hi) {
  PK p; p.b2 = __float22bfloat162_rn(make_float2(lo, hi)); return p.u;  // (hi<<16)|lo
}

__device__ __forceinline__ int   bcast_i(int v, int lane) {
  return __builtin_amdgcn_readlane(v, lane);
}
__device__ __forceinline__ float bcast_f(float v, int lane) {
  return __int_as_float(__builtin_amdgcn_readlane(__float_as_int(v), lane));
}

// bf16 pair unpack: u = (Lbits<<16) | Hbits
__device__ __forceinline__ float bfH(uint32_t u) { return __uint_as_float(u << 16); }
__device__ __forceinline__ float bfL(uint32_t u) { return __uint_as_float(u & 0xffff0000u); }

// -------------------------------------------------------------------------
// prep: zero bucket cursors + build Wt = bf16 transposed weights [m][n][k]
// (n-major so a lane's B-fragment = 8 contiguous bf16 = one 16B load)
// -------------------------------------------------------------------------
__global__ __launch_bounds__(256) void prep_kernel(
    const float* __restrict__ Wh, const float* __restrict__ Wl,
    __hip_bfloat16* __restrict__ Wt, int* __restrict__ cursor)
{
  if (blockIdx.x == 0 && threadIdx.x < BKT) cursor[threadIdx.x] = 0;
  int g = blockIdx.x * 256 + threadIdx.x;
  if (g < 2 * DOUT * DIN) {
    int m = g >> 14, rem = g & 16383;
    int n = rem >> 8, k = rem & 255;
    float v = (m ? Wl : Wh)[k * DOUT + n];
    Wt[g] = __float2bfloat16(v);
  }
}

// -------------------------------------------------------------------------
// Fused kernel:
//  blocks [0, NBIN): binning role — LDS counting-sort of 4096 edges into 196
//    coarse buckets (src>>8); one global atomic per (block,bucket); coalesced
//    run writes of packed (src<<16)|dst.
//  blocks [NBIN, NBIN+NGEMM): MFMA gemm role — 64 rows/block, bf16 16x16x32.
//    A staged in LDS in fragment order (conflict-free b128 read+write).
//    B frags read from global Wt (64KB, L2-resident).
//    Outputs packed bf16 HL + per-node scalars ss.
// -------------------------------------------------------------------------
__global__ __launch_bounds__(256) void fused_kernel(
    const float* __restrict__ inp, const __hip_bfloat16* __restrict__ Wt,
    const float* __restrict__ ah, const float* __restrict__ al,
    const int* __restrict__ edge, int* __restrict__ cursor,
    uint32_t* __restrict__ binned, uint32_t* __restrict__ HL,
    float2* __restrict__ ss)
{
  __shared__ __align__(16) char smem[32768];   // overlay: binning stage / A frags

  const int idx = blockIdx.x;
  const int t = threadIdx.x;

  if (idx < NBIN) {
    // ---------------- binning role ----------------
    uint32_t* stage  = (uint32_t*)smem;                 // 16384 B
    int*      hist   = (int*)(smem + 16384);            // 784 B
    int*      cur    = (int*)(smem + 17168);            // 784 B
    int*      base_g = (int*)(smem + 17952);            // 784 B
    int*      scan_s = (int*)(smem + 18736);            // 788 B

    const int e0 = idx * EPB;
    uint32_t v[EPT];
#pragma unroll
    for (int i = 0; i < EPT; i++) {
      int e = e0 + i * 256 + t;
      if (e < NE) {
        uint32_t s = (uint32_t)edge[e];
        uint32_t d = (uint32_t)edge[NE + e];
        v[i] = (s << 16) | d;            // bin = v >> 24 = src >> 8
      } else {
        v[i] = 0xFFFFFFFFu;              // bin 255 -> skipped
      }
    }
    for (int b = t; b < BKT; b += 256) { hist[b] = 0; cur[b] = 0; }
    __syncthreads();
#pragma unroll
    for (int i = 0; i < EPT; i++) {
      int b = v[i] >> 24;
      if (b < BKT) atomicAdd(&hist[b], 1);
    }
    __syncthreads();
    if (t == 0) {
      int acc = 0;
      for (int b = 0; b < BKT; b++) { scan_s[b] = acc; acc += hist[b]; }
      scan_s[BKT] = acc;
    }
    __syncthreads();
    for (int b = t; b < BKT; b += 256) {
      int h = hist[b];
      base_g[b] = h ? atomicAdd(&cursor[b], h) : 0;
    }
    __syncthreads();
#pragma unroll
    for (int i = 0; i < EPT; i++) {
      int b = v[i] >> 24;
      if (b < BKT) {
        int pos = atomicAdd(&cur[b], 1);
        stage[scan_s[b] + pos] = v[i];
      }
    }
    __syncthreads();
    const int total = scan_s[BKT];
    for (int i = t; i < total; i += 256) {
      int lo = 0, hi = BKT - 1;
      while (lo < hi) { int mid = (lo + hi + 1) >> 1; if (scan_s[mid] <= i) lo = mid; else hi = mid - 1; }
      int ofs = base_g[lo] + (i - scan_s[lo]);
      if (ofs < BCAP) binned[(size_t)lo * BCAP + ofs] = stage[i];
    }
    return;
  }

  // ---------------- MFMA gemm role ----------------
  frag8* asmem = (frag8*)smem;             // 2048 chunks x 16B
  const int gid = idx - NBIN;              // 0 .. NGEMM-1
  const int n0 = gid * MTB;
  const int lane = t & 63;
  const int w = t >> 6;                    // wave id: rows w*16..w*16+15
  const int quad = lane >> 4, nn = lane & 15;

  // Stage A tile (64 rows x 256 k) as bf16 in fragment order:
  // chunk c: bits [10:9]=w, [8:6]=q(kstep), [5:4]=quad, [3:0]=r.
  // Lane-consecutive chunk writes -> conflict-free ds_write_b128.
  const float4* inp4 = (const float4*)inp;
#pragma unroll
  for (int i = 0; i < 8; i++) {
    int c = i * 256 + t;
    int r = c & 15;
    int cc = c >> 4;
    int qd = cc & 3;
    int wq = cc >> 2;                      // w*8 + q
    int row = ((wq >> 3) << 4) + r;
    int k0 = ((wq & 7) << 5) + (qd << 3);
    int node = n0 + row;
    float4 a0 = make_float4(0.f, 0.f, 0.f, 0.f), a1 = a0;
    if (node < NN) {
      a0 = inp4[(size_t)node * 64 + (k0 >> 2)];
      a1 = inp4[(size_t)node * 64 + (k0 >> 2) + 1];
    }
    CH ch;
    ch.u[0] = pk2(a0.x, a0.y);
    ch.u[1] = pk2(a0.z, a0.w);
    ch.u[2] = pk2(a1.x, a1.y);
    ch.u[3] = pk2(a1.z, a1.w);
    asmem[c] = ch.v;
  }
  __syncthreads();

  fragc accH[4], accL[4];
#pragma unroll
  for (int c = 0; c < 4; c++) {
    accH[c] = (fragc){0.f, 0.f, 0.f, 0.f};
    accL[c] = (fragc){0.f, 0.f, 0.f, 0.f};
  }

  const frag8* Wt8 = (const frag8*)Wt;     // [m*64 + n'][32 k-chunks]
#pragma unroll
  for (int q = 0; q < 8; q++) {
    frag8 af = asmem[(w << 9) + (q << 6) + lane];   // A[m=nn][k=q*32+quad*8+j]
#pragma unroll
    for (int c = 0; c < 4; c++) {
      frag8 bh = Wt8[(c * 16 + nn) * 32 + q * 4 + quad];        // B[k][n=c*16+nn]
      frag8 bl = Wt8[(64 + c * 16 + nn) * 32 + q * 4 + quad];
      accH[c] = __builtin_amdgcn_mfma_f32_16x16x32_bf16(af, bh, accH[c], 0, 0, 0);
      accL[c] = __builtin_amdgcn_mfma_f32_16x16x32_bf16(af, bl, accL[c], 0, 0, 0);
    }
  }

  // Epilogue: C/D mapping col=lane&15 (n), row=quad*4+reg (m89-verified).
  float ahv[4], alv[4];
#pragma unroll
  for (int c = 0; c < 4; c++) { ahv[c] = ah[c * 16 + nn]; alv[c] = al[c * 16 + nn]; }
#pragma unroll
  for (int r = 0; r < 4; r++) {
    int node = n0 + (w << 4) + (quad << 2) + r;
    float sH = 0.f, sL = 0.f;
#pragma unroll
    for (int c = 0; c < 4; c++) {
      float hH = leaky01(accH[c][r]);
      float hL = leaky01(accL[c][r]);
      if (node < NN) HL[(size_t)node * DOUT + c * 16 + nn] = pk2(hH, hL);
      sH += hH * ahv[c];
      sL += hL * alv[c];
    }
#pragma unroll
    for (int off = 1; off < 16; off <<= 1) {   // reduce over n within quad
      sH += __shfl_xor(sH, off);
      sL += __shfl_xor(sL, off);
    }
    if (nn == 0 && node < NN) ss[node] = make_float2(sH, sL);
  }
}

// -------------------------------------------------------------------------
// CSR build: one 1024-thread block per coarse bucket. LDS per-node counters;
// scattered writes confined to this bucket's 98 KB col window (L2-local).
// -------------------------------------------------------------------------
__global__ __launch_bounds__(1024) void csr_kernel(
    const uint32_t* __restrict__ binned, const int* __restrict__ cursor,
    int* __restrict__ col)
{
  __shared__ int cnt[256];
  const int b = blockIdx.x;                // 0..BKT-1
  const int t = threadIdx.x;
  if (t < 256) cnt[t] = 0;
  __syncthreads();
  int n = cursor[b]; if (n > BCAP) n = BCAP;
  const uint32_t* eb = binned + (size_t)b * BCAP;
  for (int i = t; i < n; i += 1024) {
    uint32_t v = eb[i];
    int src = v >> 16, dst = v & 0xffff;
    int pos = atomicAdd(&cnt[src & 255], 1);
    if (pos < CAPD) col[(size_t)src * CAPS + 1 + pos] = dst;
  }
  __syncthreads();
  if (t < 256) {
    int node = (b << 8) + t;
    if (node < NN) {
      int c = cnt[t]; if (c > CAPD) c = CAPD;
      col[(size_t)node * CAPS] = c;
    }
  }
}

// -------------------------------------------------------------------------
// agg: one wave per node; lane d owns feature dim d. No float atomics.
// j-loop unrolled x8 -> 8 outstanding gathers per wave.
// -------------------------------------------------------------------------
__global__ __launch_bounds__(256) void agg_kernel(
    const uint32_t* __restrict__ HL, const float2* __restrict__ ss,
    const int* __restrict__ col, float* __restrict__ out)
{
  int wave = (blockIdx.x * blockDim.x + threadIdx.x) >> 6;
  int lane = threadIdx.x & 63;
  if (wave >= NN) return;
  const int n = wave;
  const int* cl = col + (size_t)n * CAPS;
  int d = cl[0]; if (d > CAPD) d = CAPD;

  const float2 sn = ss[n];

  float accH = 0.f, accL = 0.f, rsH = 0.f, rsL = 0.f;

  for (int base = 0; base < d; base += 64) {
    int m = d - base; if (m > 64) m = 64;
    int   dst_l = 0;
    float eh_l = 0.f, el_l = 0.f;
    if (lane < m) {
      dst_l = cl[1 + base + lane];
      float2 sd = ss[dst_l];
      float xh = sn.x - sd.x;
      xh = (xh >= 0.f) ? xh : 0.2f * xh;
      eh_l = __expf(-xh);
      float xl = sn.y + sd.y;
      xl = (xl >= 0.f) ? xl : 0.2f * xl;
      el_l = __expf(-xl);
    }
    int j = 0;
    for (; j + 8 <= m; j += 8) {
      uint32_t u[8]; float eh[8], el[8];
#pragma unroll
      for (int x = 0; x < 8; x++) {
        int dd = bcast_i(dst_l, j + x);
        u[x]  = HL[((uint32_t)dd << 6) + lane];
        eh[x] = bcast_f(eh_l, j + x);
        el[x] = bcast_f(el_l, j + x);
      }
#pragma unroll
      for (int x = 0; x < 8; x++) {
        accH += eh[x] * bfH(u[x]); accL += el[x] * bfL(u[x]);
        rsH += eh[x]; rsL += el[x];
      }
    }
    for (; j < m; j++) {
      int      dst = bcast_i(dst_l, j);
      float    eh  = bcast_f(eh_l, j);
      float    el  = bcast_f(el_l, j);
      uint32_t u   = HL[((uint32_t)dst << 6) + lane];
      accH += eh * bfH(u);
      accL += el * bfL(u);
      rsH += eh;
      rsL += el;
    }
  }

  float oh = accH / (rsH + 1e-16f);
  float ol = accL / (rsL + 1e-16f);
  out[(size_t)n * 128 + lane]      = leaky01(oh);
  out[(size_t)n * 128 + 64 + lane] = leaky01(ol);
}

// -------------------------------------------------------------------------
extern "C" void kernel_launch(void* const* d_in, const int* in_sizes, int n_in,
                              void* d_out, int out_size, void* d_ws, size_t ws_size,
                              hipStream_t stream) {
  const float* inp  = (const float*)d_in[0];
  const int*   edge = (const int*)d_in[1];
  const float* Wh   = (const float*)d_in[2];
  const float* Wl   = (const float*)d_in[3];
  const float* ah   = (const float*)d_in[4];
  const float* al   = (const float*)d_in[5];
  float* out = (float*)d_out;

  char* ws = (char*)d_ws;
  uint32_t* HL     = (uint32_t*)(ws + 0);          // 12,800,000 B
  float2*   ss     = (float2*)  (ws + 12800000);   //    400,000 B
  int*      col    = (int*)     (ws + 13200000);   // 19,200,000 B
  uint32_t* binned = (uint32_t*)(ws + 32400000);   //  8,028,160 B
  int*      cursor = (int*)     (ws + 40428160);   //        784 B
  // Wt (64 KB bf16 weights) overlays col's first bytes: read only during
  // fused_kernel; csr_kernel overwrites col strictly afterwards.
  __hip_bfloat16* Wt = (__hip_bfloat16*)(ws + 13200000);

  prep_kernel<<<128, 256, 0, stream>>>(Wh, Wl, Wt, cursor);
  fused_kernel<<<NBIN + NGEMM, 256, 0, stream>>>(inp, Wt, ah, al, edge,
                                                 cursor, binned, HL, ss);
  csr_kernel<<<BKT, 1024, 0, stream>>>(binned, cursor, col);
  agg_kernel<<<NN / 4, 256, 0, stream>>>(HL, ss, col, out);
}